// Round 4
// baseline (413.837 us; speedup 1.0000x reference)
//
#include <hip/hip_runtime.h>

// Problem constants (from reference)
#define NNZ        524288
#define DDIM       256
#define N_MENTIONS 65536

typedef float f4 __attribute__((ext_vector_type(4)));

// ---------------------------------------------------------------------------
// Kernel 1: build row_start[0 .. N_MENTIONS] in d_ws from sorted spm_rows.
// Thread j writes row_start[r] = j for all r in (spm_rows[j-1], spm_rows[j]];
// disjoint union covers [0, N_MENTIONS] exactly once (handles empty rows),
// so the 0xAA-poisoned workspace is fully overwritten every call.
// ---------------------------------------------------------------------------
__global__ __launch_bounds__(256) void build_row_start_kernel(
    const int* __restrict__ spm_rows,   // [NNZ] sorted
    int*       __restrict__ row_start)  // [N_MENTIONS + 1]
{
    const int j = blockIdx.x * blockDim.x + threadIdx.x;
    if (j > NNZ) return;
    const int cur  = (j < NNZ) ? spm_rows[j] : N_MENTIONS;
    const int prev = (j > 0)   ? spm_rows[j - 1] : -1;
    for (int r = prev + 1; r <= cur; ++r) row_start[r] = j;
}

// ---------------------------------------------------------------------------
// Kernel 2: one wave per mention row. Lane l owns float4 columns [4l, 4l+4).
// start/end from row_start (2 wave-uniform loads). Codes/vals for the segment
// (max ~30 nnz << 64) are lane-loaded once, consumed via __shfl broadcast.
// Gathers are NON-TEMPORAL (reuse is only ever caught at L3; don't churn L2)
// and issued in batches of 8 so one vmcnt wait covers an average row.
// ---------------------------------------------------------------------------
__global__ __launch_bounds__(256) void mention_csr_kernel(
    const float* __restrict__ token_ft,   // [N_TOKENS, 256]
    const int*   __restrict__ token_code, // [NNZ]
    const float* __restrict__ spm_vals,   // [NNZ]
    const int*   __restrict__ row_start,  // [N_MENTIONS + 1]
    float*       __restrict__ out)        // [N_MENTIONS, 256]
{
    const int wave = threadIdx.x >> 6;            // 0..3
    const int lane = threadIdx.x & 63;
    const int row  = (blockIdx.x << 2) + wave;    // mention row

    const int start = row_start[row];
    const int end   = row_start[row + 1];

    f4 acc0 = 0.f;
    f4 acc1 = 0.f;

    for (int base = start; base < end; base += 64) {
        const int count = min(64, end - base);
        int   code_l = 0;
        float val_l  = 0.f;
        if (lane < count) {
            code_l = token_code[base + lane];
            val_l  = spm_vals[base + lane];
        }

        int i = 0;
        for (; i + 8 <= count; i += 8) {
            int   c[8]; float v[8];
            #pragma unroll
            for (int u = 0; u < 8; ++u) {
                c[u] = __shfl(code_l, i + u);
                v[u] = __shfl(val_l,  i + u);
            }
            f4 f[8];
            #pragma unroll
            for (int u = 0; u < 8; ++u)
                f[u] = __builtin_nontemporal_load(
                    ((const f4*)(token_ft + (size_t)c[u] * DDIM)) + lane);
            #pragma unroll
            for (int u = 0; u < 8; u += 2) {
                acc0 += f[u]     * v[u];
                acc1 += f[u + 1] * v[u + 1];
            }
        }
        for (; i + 4 <= count; i += 4) {
            int   c[4]; float v[4];
            #pragma unroll
            for (int u = 0; u < 4; ++u) {
                c[u] = __shfl(code_l, i + u);
                v[u] = __shfl(val_l,  i + u);
            }
            f4 f[4];
            #pragma unroll
            for (int u = 0; u < 4; ++u)
                f[u] = __builtin_nontemporal_load(
                    ((const f4*)(token_ft + (size_t)c[u] * DDIM)) + lane);
            acc0 += f[0] * v[0];
            acc1 += f[1] * v[1];
            acc0 += f[2] * v[2];
            acc1 += f[3] * v[3];
        }
        for (; i < count; ++i) {
            const int   cc = __shfl(code_l, i);
            const float vv = __shfl(val_l, i);
            const f4 f = __builtin_nontemporal_load(
                ((const f4*)(token_ft + (size_t)cc * DDIM)) + lane);
            acc0 += f * vv;
        }
    }

    acc0 += acc1;
    // Always store (zeros for empty segments — d_out is poisoned by harness).
    __builtin_nontemporal_store(acc0, ((f4*)(out + (size_t)row * DDIM)) + lane);
}

// ---------------------------------------------------------------------------
// Fallback (ws too small): binary-search kernel. Kept for safety.
// ---------------------------------------------------------------------------
__global__ __launch_bounds__(256) void mention_segsum_kernel(
    const float* __restrict__ token_ft,
    const int*   __restrict__ token_code,
    const int*   __restrict__ spm_rows,
    const float* __restrict__ spm_vals,
    float*       __restrict__ out)
{
    const int wave = threadIdx.x >> 6;
    const int lane = threadIdx.x & 63;
    const int row  = (blockIdx.x << 2) + wave;

    int lo = 0, hi = NNZ;
    while (lo < hi) {
        int mid = (lo + hi) >> 1;
        if (spm_rows[mid] < row) lo = mid + 1; else hi = mid;
    }
    const int start = lo;
    hi = NNZ;
    while (lo < hi) {
        int mid = (lo + hi) >> 1;
        if (spm_rows[mid] < row + 1) lo = mid + 1; else hi = mid;
    }
    const int end = lo;

    f4 acc = 0.f;
    for (int k = start; k < end; ++k) {
        const int   code = token_code[k];
        const float v    = spm_vals[k];
        const f4 ft = ((const f4*)(token_ft + (size_t)code * DDIM))[lane];
        acc += ft * v;
    }
    ((f4*)(out + (size_t)row * DDIM))[lane] = acc;
}

extern "C" void kernel_launch(void* const* d_in, const int* in_sizes, int n_in,
                              void* d_out, int out_size, void* d_ws, size_t ws_size,
                              hipStream_t stream) {
    const float* token_ft   = (const float*)d_in[0];
    const int*   token_code = (const int*)d_in[1];
    const int*   spm_rows   = (const int*)d_in[2];
    const float* spm_vals   = (const float*)d_in[3];
    float*       out        = (float*)d_out;

    const size_t need = (size_t)(N_MENTIONS + 1) * sizeof(int);
    if (ws_size >= need) {
        int* row_start = (int*)d_ws;
        build_row_start_kernel<<<(NNZ + 1 + 255) / 256, 256, 0, stream>>>(
            spm_rows, row_start);
        mention_csr_kernel<<<N_MENTIONS / 4, 256, 0, stream>>>(
            token_ft, token_code, spm_vals, row_start, out);
    } else {
        mention_segsum_kernel<<<N_MENTIONS / 4, 256, 0, stream>>>(
            token_ft, token_code, spm_rows, spm_vals, out);
    }
}